// Round 3
// baseline (231.739 us; speedup 1.0000x reference)
//
#include <hip/hip_runtime.h>
#include <math.h>

// Problem constants
#define BB 4
#define NN 8192
#define KK 16
#define DD 128
#define GG 32
#define NPTS (BB * NN)          // 32768
#define FBLOCKS 1024            // 4 blocks/CU on 256 CUs -> all resident (capacity = 1024)
#define PTS_PER_BLOCK 32        // 8 point-slots x 4 iterations
#define BN_EPS 1e-5f

// ---------------------------------------------------------------------------
// Kernel 0: transpose proj_w [D,D] -> wt[c][d] = w[d][c]
// ---------------------------------------------------------------------------
__global__ void transpose_w(const float* __restrict__ w, float* __restrict__ wt) {
    int i = blockIdx.x * 256 + threadIdx.x;   // 16384 elements
    int d = i >> 7;
    int c = i & 127;
    wt[c * 128 + d] = w[d * 128 + c];
}

// ---------------------------------------------------------------------------
// Kernel 1: h[p][d] = sum_c x[p][c] * wt[c][d]
// ---------------------------------------------------------------------------
__global__ __launch_bounds__(256) void gemm_h(const float* __restrict__ x,
                                              const float* __restrict__ wt,
                                              float* __restrict__ h) {
    __shared__ float xs[64][128];
    const int block_row = blockIdx.x * 64;
    const int t = threadIdx.x;

    const float4* xg = reinterpret_cast<const float4*>(x + (size_t)block_row * 128);
    float4* xs4 = reinterpret_cast<float4*>(&xs[0][0]);
#pragma unroll
    for (int i = 0; i < 8; ++i) xs4[t + 256 * i] = xg[t + 256 * i];
    __syncthreads();

    const int ty = t >> 5;          // 0..7
    const int tx = t & 31;          // 0..31
    const int r0 = ty * 8;
    const int c0 = tx * 4;

    float acc[8][4];
#pragma unroll
    for (int r = 0; r < 8; ++r)
#pragma unroll
        for (int j = 0; j < 4; ++j) acc[r][j] = 0.f;

    for (int c4 = 0; c4 < 32; ++c4) {
        float4 wv[4];
#pragma unroll
        for (int j = 0; j < 4; ++j)
            wv[j] = *reinterpret_cast<const float4*>(wt + (size_t)(c4 * 4 + j) * 128 + c0);
#pragma unroll
        for (int r = 0; r < 8; ++r) {
            float4 xv = *reinterpret_cast<const float4*>(&xs[r0 + r][c4 * 4]);
            const float xc[4] = {xv.x, xv.y, xv.z, xv.w};
#pragma unroll
            for (int j = 0; j < 4; ++j) {
                acc[r][0] = fmaf(xc[j], wv[j].x, acc[r][0]);
                acc[r][1] = fmaf(xc[j], wv[j].y, acc[r][1]);
                acc[r][2] = fmaf(xc[j], wv[j].z, acc[r][2]);
                acc[r][3] = fmaf(xc[j], wv[j].w, acc[r][3]);
            }
        }
    }

#pragma unroll
    for (int r = 0; r < 8; ++r) {
        float4 o = make_float4(acc[r][0], acc[r][1], acc[r][2], acc[r][3]);
        *reinterpret_cast<float4*>(h + (size_t)(block_row + r0 + r) * 128 + c0) = o;
    }
}

// ---------------------------------------------------------------------------
// Manual grid barrier. Each (cnt,gen) pair is used exactly ONCE per kernel
// invocation; flags are zeroed by hipMemsetAsync at the start of every
// kernel_launch (survives the harness 0xAA ws-poison). Arrival RMW is
// ACQ_REL at agent scope (release: makes this block's prior global stores
// visible device-wide; acquire for the last arriver: sees everyone's).
// Waiters spin on a RELAXED agent load (no cache-inv hammering), then do one
// ACQUIRE load on exit.
// ---------------------------------------------------------------------------
__device__ __forceinline__ void grid_barrier(int* cnt, int* gen) {
    __syncthreads();
    if (threadIdx.x == 0) {
        int prev = __hip_atomic_fetch_add(cnt, 1, __ATOMIC_ACQ_REL, __HIP_MEMORY_SCOPE_AGENT);
        if (prev == FBLOCKS - 1) {
            __hip_atomic_store(gen, 1, __ATOMIC_RELEASE, __HIP_MEMORY_SCOPE_AGENT);
        } else {
            while (__hip_atomic_load(gen, __ATOMIC_RELAXED, __HIP_MEMORY_SCOPE_AGENT) == 0) {
                __builtin_amdgcn_s_sleep(8);
            }
            (void)__hip_atomic_load(gen, __ATOMIC_ACQUIRE, __HIP_MEMORY_SCOPE_AGENT);
        }
    }
    __syncthreads();
}

// ---------------------------------------------------------------------------
// Kernel 2 (fused, normal launch + manual barriers):
//   phase 1: gather+encode+max (aggregates stay in registers) + BN partials
//   phase 2: first 128 blocks -> per-channel stats
//   phase 3: y = acc*A + C written ONCE to out
// XCD batch-affinity swizzle: block (xcd = blk&7) handles batch xcd>>1, so
// each XCD's gathered-h working set is its own 4 MB batch slice (fits L2).
// ---------------------------------------------------------------------------
__global__ __launch_bounds__(256, 4) void fused_gbn(const float* __restrict__ h,
                                                    const float* __restrict__ xyz,
                                                    const int* __restrict__ knn,
                                                    const float* __restrict__ coor,
                                                    const float* __restrict__ scale,
                                                    const float* __restrict__ bnw,
                                                    const float* __restrict__ bnb,
                                                    float* __restrict__ out,
                                                    float* __restrict__ partials,
                                                    float* __restrict__ stats,
                                                    int* __restrict__ flags) {
    const int t = threadIdx.x;
    const int g = t & 31;    // group id (channels 4g..4g+3)
    const int sub = t >> 5;  // point slot 0..7

    // XCD batch-affinity swizzle (bijective over 1024 blocks)
    const int xcd = blockIdx.x & 7;
    const int jj = blockIdx.x >> 3;                 // 0..127
    const int slot = ((xcd & 1) << 7) + jj;         // 0..255 within batch
    const int b = xcd >> 1;                         // batch 0..3
    const int pbase = (b << 13) + (slot << 5);      // batch*8192 + slot*32

    const float c0w = coor[g * 3 + 0];
    const float c1w = coor[g * 3 + 1];
    const float c2w = coor[g * 3 + 2];
    const float sg = scale[g];
    const float s2 = sg * sg;

    float lsum[4] = {0.f, 0.f, 0.f, 0.f};
    float lsq[4]  = {0.f, 0.f, 0.f, 0.f};
    float4 accv[4];

    // ---- phase 1: gather + encode + max over K ----
#pragma unroll
    for (int it = 0; it < 4; ++it) {
        const int p = pbase + it * 8 + sub;
        const float* ctr = xyz + (size_t)p * 3;
        const float cx = ctr[0], cy = ctr[1], cz = ctr[2];
        const int* kn = knn + (size_t)p * KK;

        float4 acc = make_float4(-INFINITY, -INFINITY, -INFINITY, -INFINITY);

#pragma unroll
        for (int k = 0; k < KK; ++k) {
            const int idx = kn[k];
            const int row = (b << 13) + idx;
            const float* nb = xyz + (size_t)row * 3;
            const float rx = nb[0] - cx;
            const float ry = nb[1] - cy;
            const float rz = nb[2] - cz;
            const float r2 = rx * rx + ry * ry + rz * rz;
            const float e = rx * c0w + ry * c1w + rz * c2w + r2 * s2;
            const float4 hv = *reinterpret_cast<const float4*>(h + (size_t)row * 128 + g * 4);
            acc.x = fmaxf(acc.x, hv.x + e);
            acc.y = fmaxf(acc.y, hv.y + e);
            acc.z = fmaxf(acc.z, hv.z + e);
            acc.w = fmaxf(acc.w, hv.w + e);
        }

        accv[it] = acc;
        lsum[0] += acc.x; lsum[1] += acc.y; lsum[2] += acc.z; lsum[3] += acc.w;
        lsq[0] += acc.x * acc.x; lsq[1] += acc.y * acc.y;
        lsq[2] += acc.z * acc.z; lsq[3] += acc.w * acc.w;
    }

    // block reduction across the 8 point-slots
    __shared__ float red[8][128];
#pragma unroll
    for (int j = 0; j < 4; ++j) red[sub][g * 4 + j] = lsum[j];
    __syncthreads();
    if (t < 128) {
        float s = 0.f;
#pragma unroll
        for (int s8 = 0; s8 < 8; ++s8) s += red[s8][t];
        partials[(size_t)t * FBLOCKS + blockIdx.x] = s;
    }
    __syncthreads();
#pragma unroll
    for (int j = 0; j < 4; ++j) red[sub][g * 4 + j] = lsq[j];
    __syncthreads();
    if (t < 128) {
        float q = 0.f;
#pragma unroll
        for (int s8 = 0; s8 < 8; ++s8) q += red[s8][t];
        partials[(size_t)(128 + t) * FBLOCKS + blockIdx.x] = q;
    }

    grid_barrier(flags + 0, flags + 1);

    // ---- phase 2: per-channel stats (first 128 blocks) ----
    if (blockIdx.x < 128) {
        const int ch = blockIdx.x;
        const float* ps = partials + (size_t)ch * FBLOCKS;
        const float* pq = partials + (size_t)(128 + ch) * FBLOCKS;
        float s = 0.f, q = 0.f;
        for (int i = t; i < FBLOCKS; i += 256) { s += ps[i]; q += pq[i]; }
        __shared__ float rs[256], rq[256];
        rs[t] = s; rq[t] = q;
        __syncthreads();
        for (int off = 128; off > 0; off >>= 1) {
            if (t < off) { rs[t] += rs[t + off]; rq[t] += rq[t + off]; }
            __syncthreads();
        }
        if (t == 0) {
            const float inv_n = 1.0f / (float)NPTS;
            const float mean = rs[0] * inv_n;
            const float var = rq[0] * inv_n - mean * mean;
            const float rstd = rsqrtf(var + BN_EPS);
            const float A = rstd * bnw[ch];
            stats[ch] = A;
            stats[128 + ch] = bnb[ch] - mean * A;
        }
    }

    grid_barrier(flags + 2, flags + 3);

    // ---- phase 3: apply BN to register-resident aggregates, single write ----
    const float4 A = *reinterpret_cast<const float4*>(stats + g * 4);
    const float4 C = *reinterpret_cast<const float4*>(stats + 128 + g * 4);
#pragma unroll
    for (int it = 0; it < 4; ++it) {
        const int p = pbase + it * 8 + sub;
        float4 v = accv[it];
        v.x = fmaf(v.x, A.x, C.x);
        v.y = fmaf(v.y, A.y, C.y);
        v.z = fmaf(v.z, A.z, C.z);
        v.w = fmaf(v.w, A.w, C.w);
        *reinterpret_cast<float4*>(out + (size_t)p * 128 + g * 4) = v;
    }
}

// ---------------------------------------------------------------------------
extern "C" void kernel_launch(void* const* d_in, const int* in_sizes, int n_in,
                              void* d_out, int out_size, void* d_ws, size_t ws_size,
                              hipStream_t stream) {
    const float* x      = (const float*)d_in[0];
    const float* xyz    = (const float*)d_in[1];
    const int*   knn    = (const int*)d_in[2];
    const float* proj_w = (const float*)d_in[3];
    const float* coor   = (const float*)d_in[4];
    const float* scale  = (const float*)d_in[5];
    const float* bnw    = (const float*)d_in[6];
    const float* bnb    = (const float*)d_in[7];
    float* out = (float*)d_out;

    char* ws = (char*)d_ws;
    size_t off = 0;
    float* h        = (float*)(ws + off); off += (size_t)NPTS * DD * 4;       // 16 MB
    float* wt       = (float*)(ws + off); off += 65536;                        // 64 KB
    float* partials = (float*)(ws + off); off += (size_t)2 * 128 * FBLOCKS * 4; // 1 MB
    float* stats    = (float*)(ws + off); off += 1024;                         // 1 KB
    int*   flags    = (int*)(ws + off);                                        // 16 B

    hipMemsetAsync(flags, 0, 16, stream);
    transpose_w<<<64, 256, 0, stream>>>(proj_w, wt);
    gemm_h<<<NPTS / 64, 256, 0, stream>>>(x, wt, h);
    fused_gbn<<<FBLOCKS, 256, 0, stream>>>(h, xyz, knn, coor, scale, bnw, bnb,
                                           out, partials, stats, flags);
}

// Round 4
// 174.788 us; speedup vs baseline: 1.3258x; 1.3258x over previous
//
#include <hip/hip_runtime.h>
#include <math.h>

// Problem constants
#define BB 4
#define NN 8192
#define KK 16
#define DD 128
#define NPTS (BB * NN)          // 32768
#define FBLOCKS 1024            // 4 blocks/CU on 256 CUs -> all resident
#define BN_EPS 1e-5f

// ---------------------------------------------------------------------------
// Kernel 0: transpose proj_w [D,D] -> wt[c][d] = w[d][c]
// ---------------------------------------------------------------------------
__global__ void transpose_w(const float* __restrict__ w, float* __restrict__ wt) {
    int i = blockIdx.x * 256 + threadIdx.x;   // 16384 elements
    int d = i >> 7;
    int c = i & 127;
    wt[c * 128 + d] = w[d * 128 + c];
}

// ---------------------------------------------------------------------------
// Kernel 1: h[p][d] = sum_c x[p][c] * wt[c][d]
// 32-row tile / block -> 1024 blocks (4/CU, 16 waves/CU). Thread tile 4x4.
// ---------------------------------------------------------------------------
__global__ __launch_bounds__(256) void gemm_h(const float* __restrict__ x,
                                              const float* __restrict__ wt,
                                              float* __restrict__ h) {
    __shared__ float xs[32][128];
    const int block_row = blockIdx.x * 32;
    const int t = threadIdx.x;

    const float4* xg = reinterpret_cast<const float4*>(x + (size_t)block_row * 128);
    float4* xs4 = reinterpret_cast<float4*>(&xs[0][0]);
#pragma unroll
    for (int i = 0; i < 4; ++i) xs4[t + 256 * i] = xg[t + 256 * i];
    __syncthreads();

    const int ty = t >> 5;          // 0..7
    const int tx = t & 31;          // 0..31
    const int r0 = ty * 4;
    const int c0 = tx * 4;

    float acc[4][4];
#pragma unroll
    for (int r = 0; r < 4; ++r)
#pragma unroll
        for (int j = 0; j < 4; ++j) acc[r][j] = 0.f;

    for (int c4 = 0; c4 < 32; ++c4) {
        float4 wv[4];
#pragma unroll
        for (int j = 0; j < 4; ++j)
            wv[j] = *reinterpret_cast<const float4*>(wt + (size_t)(c4 * 4 + j) * 128 + c0);
#pragma unroll
        for (int r = 0; r < 4; ++r) {
            float4 xv = *reinterpret_cast<const float4*>(&xs[r0 + r][c4 * 4]);
            const float xc[4] = {xv.x, xv.y, xv.z, xv.w};
#pragma unroll
            for (int j = 0; j < 4; ++j) {
                acc[r][0] = fmaf(xc[j], wv[j].x, acc[r][0]);
                acc[r][1] = fmaf(xc[j], wv[j].y, acc[r][1]);
                acc[r][2] = fmaf(xc[j], wv[j].z, acc[r][2]);
                acc[r][3] = fmaf(xc[j], wv[j].w, acc[r][3]);
            }
        }
    }

#pragma unroll
    for (int r = 0; r < 4; ++r) {
        float4 o = make_float4(acc[r][0], acc[r][1], acc[r][2], acc[r][3]);
        *reinterpret_cast<float4*>(h + (size_t)(block_row + r0 + r) * 128 + c0) = o;
    }
}

// ---------------------------------------------------------------------------
// Kernel 2 (fused): gather+encode+max -> atomic BN accumulate -> single
// atomic-RMW grid barrier -> per-block redundant stats -> apply+store.
// ALL cross-block communication is atomic RMWs (coherent point), so no
// fences / cache-maintenance ops are needed or emitted.
// gacc: [0..127] channel sums, [128..255] channel sumsq (atomicAdd targets).
// cnt: arrival counter. gen[32]: replicated release flags.
// ---------------------------------------------------------------------------
__global__ __launch_bounds__(256, 4) void fused_gbn(const float* __restrict__ h,
                                                    const float* __restrict__ xyz,
                                                    const int* __restrict__ knn,
                                                    const float* __restrict__ coor,
                                                    const float* __restrict__ scale,
                                                    const float* __restrict__ bnw,
                                                    const float* __restrict__ bnb,
                                                    float* __restrict__ out,
                                                    float* gacc,
                                                    int* cnt,
                                                    int* gen) {
    const int t = threadIdx.x;
    const int g = t & 31;    // group id (channels 4g..4g+3)
    const int sub = t >> 5;  // point slot 0..7

    // XCD batch-affinity swizzle (bijective over 1024 blocks; perf-only)
    const int xcd = blockIdx.x & 7;
    const int jj = blockIdx.x >> 3;                 // 0..127
    const int slot = ((xcd & 1) << 7) + jj;         // 0..255 within batch
    const int b = xcd >> 1;                         // batch 0..3
    const int pbase = (b << 13) + (slot << 5);      // batch*8192 + slot*32

    const float c0w = coor[g * 3 + 0];
    const float c1w = coor[g * 3 + 1];
    const float c2w = coor[g * 3 + 2];
    const float sg = scale[g];
    const float s2 = sg * sg;

    float lsum[4] = {0.f, 0.f, 0.f, 0.f};
    float lsq[4]  = {0.f, 0.f, 0.f, 0.f};
    float4 accv[4];

    // ---- phase 1: gather + encode + max over K (acc in registers) ----
#pragma unroll
    for (int it = 0; it < 4; ++it) {
        const int p = pbase + it * 8 + sub;
        const float* ctr = xyz + (size_t)p * 3;
        const float cx = ctr[0], cy = ctr[1], cz = ctr[2];
        const int* kn = knn + (size_t)p * KK;

        float4 acc = make_float4(-INFINITY, -INFINITY, -INFINITY, -INFINITY);

#pragma unroll
        for (int k = 0; k < KK; ++k) {
            const int idx = kn[k];
            const int row = (b << 13) + idx;
            const float* nb = xyz + (size_t)row * 3;
            const float rx = nb[0] - cx;
            const float ry = nb[1] - cy;
            const float rz = nb[2] - cz;
            const float r2 = rx * rx + ry * ry + rz * rz;
            const float e = rx * c0w + ry * c1w + rz * c2w + r2 * s2;
            const float4 hv = *reinterpret_cast<const float4*>(h + (size_t)row * 128 + g * 4);
            acc.x = fmaxf(acc.x, hv.x + e);
            acc.y = fmaxf(acc.y, hv.y + e);
            acc.z = fmaxf(acc.z, hv.z + e);
            acc.w = fmaxf(acc.w, hv.w + e);
        }

        accv[it] = acc;
        lsum[0] += acc.x; lsum[1] += acc.y; lsum[2] += acc.z; lsum[3] += acc.w;
        lsq[0] += acc.x * acc.x; lsq[1] += acc.y * acc.y;
        lsq[2] += acc.z * acc.z; lsq[3] += acc.w * acc.w;
    }

    // ---- block-reduce partials in LDS, publish via atomicAdd ----
    __shared__ float red[8][128];
#pragma unroll
    for (int j = 0; j < 4; ++j) red[sub][g * 4 + j] = lsum[j];
    __syncthreads();
    if (t < 128) {
        float s = 0.f;
#pragma unroll
        for (int s8 = 0; s8 < 8; ++s8) s += red[s8][t];
        atomicAdd(&gacc[t], s);
    }
    __syncthreads();
#pragma unroll
    for (int j = 0; j < 4; ++j) red[sub][g * 4 + j] = lsq[j];
    __syncthreads();
    if (t < 128) {
        float q = 0.f;
#pragma unroll
        for (int s8 = 0; s8 < 8; ++s8) q += red[s8][t];
        atomicAdd(&gacc[128 + t], q);
    }

    // my atomic adds must be complete (at the coherent point) before arrival
    asm volatile("s_waitcnt vmcnt(0)" ::: "memory");
    __syncthreads();

    // ---- grid barrier: int RMW arrival + replicated-flag RMW polling ----
    __shared__ int s_prev;
    if (t == 0) s_prev = atomicAdd(cnt, 1);
    __syncthreads();
    if (s_prev == FBLOCKS - 1) {
        if (t < 32) atomicExch(&gen[t], 1);   // parallel publish to 32 copies
    } else if (t == 0) {
        int* mygen = gen + (blockIdx.x & 31);
        while (atomicAdd(mygen, 0) == 0) {    // RMW poll: always coherent
            __builtin_amdgcn_s_sleep(8);
        }
    }
    __syncthreads();

    // ---- redundant per-block stats from global accumulators (RMW reads) ----
    __shared__ float sA[128], sC[128];
    if (t < 128) {
        const float stot = atomicAdd(&gacc[t], 0.0f);
        const float qtot = atomicAdd(&gacc[128 + t], 0.0f);
        const float inv_n = 1.0f / (float)NPTS;
        const float mean = stot * inv_n;
        const float var = qtot * inv_n - mean * mean;
        const float rstd = rsqrtf(var + BN_EPS);
        const float A = rstd * bnw[t];
        sA[t] = A;
        sC[t] = bnb[t] - mean * A;
    }
    __syncthreads();

    // ---- apply BN to register-resident aggregates, single write ----
    const float4 A4 = make_float4(sA[g * 4], sA[g * 4 + 1], sA[g * 4 + 2], sA[g * 4 + 3]);
    const float4 C4 = make_float4(sC[g * 4], sC[g * 4 + 1], sC[g * 4 + 2], sC[g * 4 + 3]);
#pragma unroll
    for (int it = 0; it < 4; ++it) {
        const int p = pbase + it * 8 + sub;
        float4 v = accv[it];
        v.x = fmaf(v.x, A4.x, C4.x);
        v.y = fmaf(v.y, A4.y, C4.y);
        v.z = fmaf(v.z, A4.z, C4.z);
        v.w = fmaf(v.w, A4.w, C4.w);
        *reinterpret_cast<float4*>(out + (size_t)p * 128 + g * 4) = v;
    }
}

// ---------------------------------------------------------------------------
extern "C" void kernel_launch(void* const* d_in, const int* in_sizes, int n_in,
                              void* d_out, int out_size, void* d_ws, size_t ws_size,
                              hipStream_t stream) {
    const float* x      = (const float*)d_in[0];
    const float* xyz    = (const float*)d_in[1];
    const int*   knn    = (const int*)d_in[2];
    const float* proj_w = (const float*)d_in[3];
    const float* coor   = (const float*)d_in[4];
    const float* scale  = (const float*)d_in[5];
    const float* bnw    = (const float*)d_in[6];
    const float* bnb    = (const float*)d_in[7];
    float* out = (float*)d_out;

    char* ws = (char*)d_ws;
    size_t off = 0;
    float* h    = (float*)(ws + off); off += (size_t)NPTS * DD * 4;   // 16 MB
    float* wt   = (float*)(ws + off); off += 65536;                   // 64 KB
    float* gacc = (float*)(ws + off); off += 256 * 4;                 // 1 KB
    int*   cnt  = (int*)(ws + off);   off += 64;                      // counter
    int*   gen  = (int*)(ws + off);   off += 32 * 4;                  // 32 flags

    // zero accumulators + barrier state every launch (graph-capture safe)
    hipMemsetAsync(gacc, 0, 256 * 4 + 64 + 32 * 4, stream);

    transpose_w<<<64, 256, 0, stream>>>(proj_w, wt);
    gemm_h<<<NPTS / 32, 256, 0, stream>>>(x, wt, h);
    fused_gbn<<<FBLOCKS, 256, 0, stream>>>(h, xyz, knn, coor, scale, bnw, bnb,
                                           out, gacc, cnt, gen);
}

// Round 5
// 85.864 us; speedup vs baseline: 2.6989x; 2.0356x over previous
//
#include <hip/hip_runtime.h>
#include <math.h>

// Problem constants
#define BB 4
#define NN 8192
#define KK 16
#define DD 128
#define NPTS (BB * NN)          // 32768
#define FBLOCKS 1024            // 4 blocks/CU on 256 CUs -> all resident
#define BPX 128                 // blocks per xcd-group (FBLOCKS/8)
#define PAD 16                  // 64B line padding for atomic targets
#define BN_EPS 1e-5f

// ---------------------------------------------------------------------------
// Kernel 0: transpose proj_w [D,D] -> wt[c][d] = w[d][c]
// ---------------------------------------------------------------------------
__global__ void transpose_w(const float* __restrict__ w, float* __restrict__ wt) {
    int i = blockIdx.x * 256 + threadIdx.x;   // 16384 elements
    int d = i >> 7;
    int c = i & 127;
    wt[c * 128 + d] = w[d * 128 + c];
}

// ---------------------------------------------------------------------------
// Kernel 1: h[p][d] = sum_c x[p][c] * wt[c][d]
// 32-row tile / block -> 1024 blocks (4/CU, 16 waves/CU). Thread tile 4x4.
// ---------------------------------------------------------------------------
__global__ __launch_bounds__(256) void gemm_h(const float* __restrict__ x,
                                              const float* __restrict__ wt,
                                              float* __restrict__ h) {
    __shared__ float xs[32][128];
    const int block_row = blockIdx.x * 32;
    const int t = threadIdx.x;

    const float4* xg = reinterpret_cast<const float4*>(x + (size_t)block_row * 128);
    float4* xs4 = reinterpret_cast<float4*>(&xs[0][0]);
#pragma unroll
    for (int i = 0; i < 4; ++i) xs4[t + 256 * i] = xg[t + 256 * i];
    __syncthreads();

    const int ty = t >> 5;          // 0..7
    const int tx = t & 31;          // 0..31
    const int r0 = ty * 4;
    const int c0 = tx * 4;

    float acc[4][4];
#pragma unroll
    for (int r = 0; r < 4; ++r)
#pragma unroll
        for (int j = 0; j < 4; ++j) acc[r][j] = 0.f;

    for (int c4 = 0; c4 < 32; ++c4) {
        float4 wv[4];
#pragma unroll
        for (int j = 0; j < 4; ++j)
            wv[j] = *reinterpret_cast<const float4*>(wt + (size_t)(c4 * 4 + j) * 128 + c0);
#pragma unroll
        for (int r = 0; r < 4; ++r) {
            float4 xv = *reinterpret_cast<const float4*>(&xs[r0 + r][c4 * 4]);
            const float xc[4] = {xv.x, xv.y, xv.z, xv.w};
#pragma unroll
            for (int j = 0; j < 4; ++j) {
                acc[r][0] = fmaf(xc[j], wv[j].x, acc[r][0]);
                acc[r][1] = fmaf(xc[j], wv[j].y, acc[r][1]);
                acc[r][2] = fmaf(xc[j], wv[j].z, acc[r][2]);
                acc[r][3] = fmaf(xc[j], wv[j].w, acc[r][3]);
            }
        }
    }

#pragma unroll
    for (int r = 0; r < 4; ++r) {
        float4 o = make_float4(acc[r][0], acc[r][1], acc[r][2], acc[r][3]);
        *reinterpret_cast<float4*>(h + (size_t)(block_row + r0 + r) * 128 + c0) = o;
    }
}

// ---------------------------------------------------------------------------
// Kernel 2 (fused): gather+encode+max -> padded atomic BN accumulate ->
// hierarchical grid barrier (read-based polling) -> redundant per-block
// stats (coherent-point loads) -> apply+store.
//
// Contention budget: gacc adds = 1024 per line (256 separate lines);
// arrival = 128 per line (8 lines) + 8 on one line; polling = system-scope
// LOADS (sc0 sc1, no RMW, no cache maintenance) at ~1/µs per block.
// ---------------------------------------------------------------------------
__global__ __launch_bounds__(256, 4) void fused_gbn(const float* __restrict__ h,
                                                    const float* __restrict__ xyz,
                                                    const int* __restrict__ knn,
                                                    const float* __restrict__ coor,
                                                    const float* __restrict__ scale,
                                                    const float* __restrict__ bnw,
                                                    const float* __restrict__ bnb,
                                                    float* __restrict__ out,
                                                    float* gacc,
                                                    int* cntx,
                                                    int* cntg,
                                                    int* genx) {
    const int t = threadIdx.x;
    const int g = t & 31;    // group id (channels 4g..4g+3)
    const int sub = t >> 5;  // point slot 0..7

    // XCD batch-affinity swizzle (bijective over 1024 blocks; perf heuristic)
    const int xcd = blockIdx.x & 7;
    const int jj = blockIdx.x >> 3;                 // 0..127
    const int slot = ((xcd & 1) << 7) + jj;         // 0..255 within batch
    const int b = xcd >> 1;                         // batch 0..3
    const int pbase = (b << 13) + (slot << 5);      // batch*8192 + slot*32

    const float c0w = coor[g * 3 + 0];
    const float c1w = coor[g * 3 + 1];
    const float c2w = coor[g * 3 + 2];
    const float sg = scale[g];
    const float s2 = sg * sg;

    float lsum[4] = {0.f, 0.f, 0.f, 0.f};
    float lsq[4]  = {0.f, 0.f, 0.f, 0.f};
    float4 accv[4];

    // ---- phase 1: gather + encode + max over K (acc in registers) ----
#pragma unroll
    for (int it = 0; it < 4; ++it) {
        const int p = pbase + it * 8 + sub;
        const float* ctr = xyz + (size_t)p * 3;
        const float cx = ctr[0], cy = ctr[1], cz = ctr[2];
        const int* kn = knn + (size_t)p * KK;

        float4 acc = make_float4(-INFINITY, -INFINITY, -INFINITY, -INFINITY);

#pragma unroll
        for (int k = 0; k < KK; ++k) {
            const int idx = kn[k];
            const int row = (b << 13) + idx;
            const float* nb = xyz + (size_t)row * 3;
            const float rx = nb[0] - cx;
            const float ry = nb[1] - cy;
            const float rz = nb[2] - cz;
            const float r2 = rx * rx + ry * ry + rz * rz;
            const float e = rx * c0w + ry * c1w + rz * c2w + r2 * s2;
            const float4 hv = *reinterpret_cast<const float4*>(h + (size_t)row * 128 + g * 4);
            acc.x = fmaxf(acc.x, hv.x + e);
            acc.y = fmaxf(acc.y, hv.y + e);
            acc.z = fmaxf(acc.z, hv.z + e);
            acc.w = fmaxf(acc.w, hv.w + e);
        }

        accv[it] = acc;
        lsum[0] += acc.x; lsum[1] += acc.y; lsum[2] += acc.z; lsum[3] += acc.w;
        lsq[0] += acc.x * acc.x; lsq[1] += acc.y * acc.y;
        lsq[2] += acc.z * acc.z; lsq[3] += acc.w * acc.w;
    }

    // ---- block-reduce partials in LDS, publish via RETURNING atomicAdd ----
    // (the returned value forces vmcnt completion at the coherent point
    //  before this block arrives at the barrier)
    __shared__ float red[8][128];
    float sink = 0.f;
#pragma unroll
    for (int j = 0; j < 4; ++j) red[sub][g * 4 + j] = lsum[j];
    __syncthreads();
    if (t < 128) {
        float s = 0.f;
#pragma unroll
        for (int s8 = 0; s8 < 8; ++s8) s += red[s8][t];
        sink += __hip_atomic_fetch_add(&gacc[t * PAD], s,
                                       __ATOMIC_RELAXED, __HIP_MEMORY_SCOPE_AGENT);
    }
    __syncthreads();
#pragma unroll
    for (int j = 0; j < 4; ++j) red[sub][g * 4 + j] = lsq[j];
    __syncthreads();
    if (t < 128) {
        float q = 0.f;
#pragma unroll
        for (int s8 = 0; s8 < 8; ++s8) q += red[s8][t];
        sink += __hip_atomic_fetch_add(&gacc[(128 + t) * PAD], q,
                                       __ATOMIC_RELAXED, __HIP_MEMORY_SCOPE_AGENT);
    }
    asm volatile("" :: "v"(sink));   // keep the returns (and their waits) live
    __syncthreads();

    // ---- hierarchical grid barrier, read-based polling ----
    if (t == 0) {
        int prev = __hip_atomic_fetch_add(&cntx[xcd * PAD], 1,
                                          __ATOMIC_RELAXED, __HIP_MEMORY_SCOPE_AGENT);
        if (prev == BPX - 1) {
            int gprev = __hip_atomic_fetch_add(cntg, 1,
                                               __ATOMIC_RELAXED, __HIP_MEMORY_SCOPE_AGENT);
            if (gprev == 7) {
#pragma unroll
                for (int xx = 0; xx < 8; ++xx)
                    __hip_atomic_store(&genx[xx * PAD], 1,
                                       __ATOMIC_RELAXED, __HIP_MEMORY_SCOPE_SYSTEM);
            }
        }
        // poll own group's flag with coherent-point LOADS (no RMW, no inv)
        while (__hip_atomic_load(&genx[xcd * PAD],
                                 __ATOMIC_RELAXED, __HIP_MEMORY_SCOPE_SYSTEM) == 0) {
            __builtin_amdgcn_s_sleep(32);
        }
    }
    __syncthreads();

    // ---- redundant per-block stats from coherent-point loads ----
    __shared__ float sA[128], sC[128];
    if (t < 128) {
        const float stot = __hip_atomic_load(&gacc[t * PAD],
                                             __ATOMIC_RELAXED, __HIP_MEMORY_SCOPE_SYSTEM);
        const float qtot = __hip_atomic_load(&gacc[(128 + t) * PAD],
                                             __ATOMIC_RELAXED, __HIP_MEMORY_SCOPE_SYSTEM);
        const float inv_n = 1.0f / (float)NPTS;
        const float mean = stot * inv_n;
        const float var = qtot * inv_n - mean * mean;
        const float rstd = rsqrtf(var + BN_EPS);
        const float A = rstd * bnw[t];
        sA[t] = A;
        sC[t] = bnb[t] - mean * A;
    }
    __syncthreads();

    // ---- apply BN to register-resident aggregates, single write ----
    const float4 A4 = make_float4(sA[g * 4], sA[g * 4 + 1], sA[g * 4 + 2], sA[g * 4 + 3]);
    const float4 C4 = make_float4(sC[g * 4], sC[g * 4 + 1], sC[g * 4 + 2], sC[g * 4 + 3]);
#pragma unroll
    for (int it = 0; it < 4; ++it) {
        const int p = pbase + it * 8 + sub;
        float4 v = accv[it];
        v.x = fmaf(v.x, A4.x, C4.x);
        v.y = fmaf(v.y, A4.y, C4.y);
        v.z = fmaf(v.z, A4.z, C4.z);
        v.w = fmaf(v.w, A4.w, C4.w);
        *reinterpret_cast<float4*>(out + (size_t)p * 128 + g * 4) = v;
    }
}

// ---------------------------------------------------------------------------
extern "C" void kernel_launch(void* const* d_in, const int* in_sizes, int n_in,
                              void* d_out, int out_size, void* d_ws, size_t ws_size,
                              hipStream_t stream) {
    const float* x      = (const float*)d_in[0];
    const float* xyz    = (const float*)d_in[1];
    const int*   knn    = (const int*)d_in[2];
    const float* proj_w = (const float*)d_in[3];
    const float* coor   = (const float*)d_in[4];
    const float* scale  = (const float*)d_in[5];
    const float* bnw    = (const float*)d_in[6];
    const float* bnb    = (const float*)d_in[7];
    float* out = (float*)d_out;

    char* ws = (char*)d_ws;
    size_t off = 0;
    float* h    = (float*)(ws + off); off += (size_t)NPTS * DD * 4;   // 16 MB
    float* wt   = (float*)(ws + off); off += 65536;                   // 64 KB
    // padded atomic area (zeroed every launch): gacc | cntx | cntg | genx
    float* gacc = (float*)(ws + off);                                 // 256*PAD floats
    size_t atomic_base = off;
    off += 256 * PAD * 4;
    int* cntx = (int*)(ws + off); off += 8 * PAD * 4;
    int* cntg = (int*)(ws + off); off += PAD * 4;
    int* genx = (int*)(ws + off); off += 8 * PAD * 4;
    size_t atomic_bytes = off - atomic_base;

    hipMemsetAsync(gacc, 0, atomic_bytes, stream);

    transpose_w<<<64, 256, 0, stream>>>(proj_w, wt);
    gemm_h<<<NPTS / 32, 256, 0, stream>>>(x, wt, h);
    fused_gbn<<<FBLOCKS, 256, 0, stream>>>(h, xyz, knn, coor, scale, bnw, bnb,
                                           out, gacc, cntx, cntg, genx);
}